// Round 13
// baseline (480.245 us; speedup 1.0000x reference)
//
#include <hip/hip_runtime.h>
#include <hip/hip_bf16.h>
#include <cstdint>

// ---------------------------------------------------------------------------
// GCN 3-layer forward, bf16 pipeline + MFMA GEMM + fp8 gather operand.
// R13: (1) gather 4 nodes/wave over contiguous combined csr range (R12's
//      2-node structure, amortized 2x further; 3-way scalar routing tree).
//      (2) build drops b_count: scatter straight into padded per-bucket
//      regions (CAP=12288, +45 sigma) with atomic cursors; tiny 1-block scan
//      of counts -> global csr offsets; b_fine compacts padded -> contiguous.
// ---------------------------------------------------------------------------

typedef unsigned short u16;
typedef unsigned int u32;
typedef unsigned char u8;
typedef __attribute__((ext_vector_type(8))) short short8v;
typedef __attribute__((ext_vector_type(4))) float f32x4;
typedef __attribute__((ext_vector_type(2))) float f32x2;

#define NBMAX 256
#define BKSH  9
#define SCH   2048
#define CAP   12288   // padded pair slots per bucket

__device__ inline u16 f2bf(float f) {
  u32 u = __float_as_uint(f);
  u += 0x7fff + ((u >> 16) & 1);  // RNE
  return (u16)(u >> 16);
}
__device__ inline float bflo(u32 u) { return __uint_as_float(u << 16); }
__device__ inline float bfhi(u32 u) { return __uint_as_float(u & 0xffff0000u); }

// --- init: block 0 detects edge dtype, block 1 zeros cursors/pooled ---------
__global__ void k_init(const int* __restrict__ ei, int* __restrict__ mode,
                       int* __restrict__ bucketCur, float* __restrict__ pooled,
                       int e, int nb) {
  if (blockIdx.x == 0) {
    __shared__ int any;
    if (threadIdx.x == 0) any = 0;
    __syncthreads();
    int lim = min(e, 2048);
    int local = 0;
    for (int i = threadIdx.x; i < lim; i += blockDim.x)
      local |= (ei[2 * i + 1] != 0);
    if (local) atomicOr(&any, 1);
    __syncthreads();
    if (threadIdx.x == 0) mode[0] = (any == 0) ? 1 : 0;
  } else {
    int i = threadIdx.x;
    if (i < nb) bucketCur[i] = 0;
    if (i < 128) pooled[i] = 0.0f;
  }
}

// --- scatter (src,dst) into PADDED bucket regions, atomic cursors -----------
__global__ __launch_bounds__(256) void b_scatter(const int* __restrict__ ei,
                                                 const int* __restrict__ mode,
                                                 int* __restrict__ bucketCur,
                                                 int* __restrict__ pairBuf,
                                                 int e, int nb) {
  __shared__ int cnt[NBMAX];
  __shared__ int pre[NBMAX];
  __shared__ int base[NBMAX];
  __shared__ int stage[2 * SCH];
  const int t = threadIdx.x;
  const int chunk0 = blockIdx.x * SCH;
  const int nloc = min(SCH, e - chunk0);
  const int m = mode[0];

  cnt[t] = 0;
  __syncthreads();

  int myS[SCH / 256], myD[SCH / 256], myB[SCH / 256], mySlot[SCH / 256];
#pragma unroll
  for (int j = 0; j < SCH / 256; ++j) {
    int li = j * 256 + t;
    myB[j] = -1;
    if (li < nloc) {
      int i = chunk0 + li;
      long long di = (long long)e + i;
      int s = m ? ei[2 * (long long)i] : ei[i];
      int d = m ? ei[2 * di] : ei[di];
      int b = d >> BKSH;
      myS[j] = s; myD[j] = d; myB[j] = b;
      mySlot[j] = atomicAdd(&cnt[b], 1);
    }
  }
  __syncthreads();

  int c0 = cnt[t];
  pre[t] = c0;
  __syncthreads();
  for (int d = 1; d < NBMAX; d <<= 1) {
    int v = (t >= d) ? pre[t - d] : 0;
    __syncthreads();
    pre[t] += v;
    __syncthreads();
  }
  int myPre = pre[t] - c0;
  if (t < nb && c0 > 0) base[t] = atomicAdd(&bucketCur[t], c0);  // bucket-rel
  __syncthreads();
  cnt[t] = myPre;
  __syncthreads();

#pragma unroll
  for (int j = 0; j < SCH / 256; ++j) {
    if (myB[j] >= 0) {
      int si = cnt[myB[j]] + mySlot[j];
      stage[2 * si] = myS[j];
      stage[2 * si + 1] = myD[j];
    }
  }
  __syncthreads();

  int wave = t >> 6, lane = t & 63;
  for (int b = wave; b < nb; b += 4) {
    int cb = pre[b] - cnt[b];
    if (cb <= 0) continue;
    int lo = cnt[b];
    int gb = base[b];
    int room = CAP - gb;
    int allowed = (room > 0) ? min(cb, room) : 0;  // overflow guard (impossible)
    size_t dst = ((size_t)b * CAP + gb) * 2;
    for (int j = lane; j < 2 * allowed; j += 64)
      pairBuf[dst + j] = stage[2 * lo + j];
  }
}

// --- tiny scan of bucket counts -> global csr base per bucket ---------------
__global__ __launch_bounds__(256) void b_bscan2(const int* __restrict__ bucketCur,
                                                int* __restrict__ bucketOff, int nb) {
  __shared__ int sh[NBMAX];
  int t = threadIdx.x;
  int c = (t < nb) ? bucketCur[t] : 0;
  sh[t] = c;
  __syncthreads();
  for (int d = 1; d < NBMAX; d <<= 1) {
    int v = (t >= d) ? sh[t - d] : 0;
    __syncthreads();
    sh[t] += v;
    __syncthreads();
  }
  if (t < nb) bucketOff[t] = sh[t] - c;  // exclusive
}

// --- per-bucket fine CSR from padded pairs -> contiguous offs/dis/csr -------
__global__ __launch_bounds__(512) void b_fine(const int* __restrict__ pairBuf,
                                              const int* __restrict__ bucketCur,
                                              const int* __restrict__ bucketOff,
                                              int* __restrict__ offs,
                                              float* __restrict__ dis,
                                              int* __restrict__ csr,
                                              int n, int e) {
  const int b = blockIdx.x;
  const int d0 = b << BKSH;
  const size_t pb = (size_t)b * CAP;
  const int cnt = bucketCur[b];
  const int lo = bucketOff[b];
  __shared__ int arr[1 << BKSH];
  __shared__ int cur[1 << BKSH];
  const int t = threadIdx.x;
  arr[t] = 0; cur[t] = 0;
  __syncthreads();
  for (int i = t; i < cnt; i += 512) {
    int d = pairBuf[2 * (pb + i) + 1];
    atomicAdd(&arr[d - d0], 1);
  }
  __syncthreads();
  int c0 = arr[t];
  __syncthreads();
  for (int dd = 1; dd < 512; dd <<= 1) {
    int v = (t >= dd) ? arr[t - dd] : 0;
    __syncthreads();
    arr[t] += v;
    __syncthreads();
  }
  int epre = arr[t] - c0;
  int gd = d0 + t;
  if (gd < n) {
    offs[gd] = lo + epre;
    dis[gd] = rsqrtf((float)c0 + 1.0f);
  }
  __syncthreads();
  arr[t] = epre;
  __syncthreads();
  for (int i = t; i < cnt; i += 512) {
    int s = pairBuf[2 * (pb + i)];
    int d = pairBuf[2 * (pb + i) + 1];
    int ld = d - d0;
    int p = lo + arr[ld] + atomicAdd(&cur[ld], 1);
    csr[p] = s;
  }
  if (b == 0 && t == 0) offs[n] = e;
}

// --- pack all 3 weights fp32 -> MFMA B-fragments bf16 (grid 24) -------------
__global__ __launch_bounds__(256) void k_wpack3(const float* __restrict__ W0,
                                                const float* __restrict__ W1,
                                                const float* __restrict__ W2,
                                                u16* __restrict__ wp) {
  int f = blockIdx.x * 256 + threadIdx.x;
  int wsel = f >> 11;
  int li = f & 2047;
  const float* W = (wsel == 0) ? W0 : (wsel == 1) ? W1 : W2;
  u16* dst = wp + (size_t)wsel * 2048 * 8;
  int ct = li >> 8, kc = (li >> 6) & 3, lane = li & 63;
  int g = lane >> 4, c = lane & 15;
  u32 o[4];
#pragma unroll
  for (int q = 0; q < 4; ++q) {
    int k = kc * 32 + g * 8 + q * 2;
    u16 e0 = f2bf(W[(size_t)k * 128 + ct * 16 + c]);
    u16 e1 = f2bf(W[(size_t)(k + 1) * 128 + ct * 16 + c]);
    o[q] = (u32)e0 | ((u32)e1 << 16);
  }
  uint4 v; v.x = o[0]; v.y = o[1]; v.z = o[2]; v.w = o[3];
  *reinterpret_cast<uint4*>(dst + (size_t)li * 8) = v;
}

// --- GEMM: tmp[r,:] = fp8( 16 * dis[r] * (h[r,:] @ W) ) via MFMA ------------
template <bool FP32IN>
__global__ __launch_bounds__(256) void k_gemm_mfma(const void* __restrict__ hin,
                                                   const u16* __restrict__ wp,
                                                   const float* __restrict__ dis,
                                                   u8* __restrict__ tmpf8, int n) {
  __shared__ float eps[64 * 132];
  const int tid = threadIdx.x;
  const int w = tid >> 6, l = tid & 63;
  const int g = l >> 4, c16 = l & 15;
  const int rowbase = blockIdx.x * 64 + w * 16;

  const short8v zero8 = {0, 0, 0, 0, 0, 0, 0, 0};
  short8v a[4];
  int ar = rowbase + c16;
  bool aok = ar < n;
#pragma unroll
  for (int kc = 0; kc < 4; ++kc) {
    if (FP32IN) {
      const float* hrow = (const float*)hin + (size_t)ar * 128;
      short8v s = zero8;
      if (aok) {
        float4 v0 = *reinterpret_cast<const float4*>(hrow + kc * 32 + g * 8);
        float4 v1 = *reinterpret_cast<const float4*>(hrow + kc * 32 + g * 8 + 4);
        s[0] = (short)f2bf(v0.x); s[1] = (short)f2bf(v0.y);
        s[2] = (short)f2bf(v0.z); s[3] = (short)f2bf(v0.w);
        s[4] = (short)f2bf(v1.x); s[5] = (short)f2bf(v1.y);
        s[6] = (short)f2bf(v1.z); s[7] = (short)f2bf(v1.w);
      }
      a[kc] = s;
    } else {
      const u16* hrow = (const u16*)hin + (size_t)ar * 128;
      a[kc] = aok ? *reinterpret_cast<const short8v*>(hrow + kc * 32 + g * 8) : zero8;
    }
  }

  f32x4 acc[8];
#pragma unroll
  for (int ct = 0; ct < 8; ++ct) acc[ct] = f32x4{0.f, 0.f, 0.f, 0.f};

#pragma unroll
  for (int ct = 0; ct < 8; ++ct) {
#pragma unroll
    for (int kc = 0; kc < 4; ++kc) {
      short8v b = *reinterpret_cast<const short8v*>(wp + ((size_t)(ct * 4 + kc) * 64 + l) * 8);
      acc[ct] = __builtin_amdgcn_mfma_f32_16x16x32_bf16(a[kc], b, acc[ct], 0, 0, 0);
    }
  }

  // scale by 16*dis[row] (x16 clears fp8 subnormal region; gather divides out)
#pragma unroll
  for (int j = 0; j < 4; ++j) {
    int rl = w * 16 + g * 4 + j;
    int gr = blockIdx.x * 64 + rl;
    float dn = (gr < n) ? dis[gr] * 16.0f : 0.f;
#pragma unroll
    for (int ct = 0; ct < 8; ++ct)
      eps[rl * 132 + ct * 16 + c16] = acc[ct][j] * dn;
  }
  __syncthreads();

  // readback: thread -> (row rl, 32-col segment), pack fp8 and store 32B
  int rl = tid >> 2, seg = tid & 3;
  int gr = blockIdx.x * 64 + rl;
  if (gr < n) {
    const float* src = &eps[rl * 132 + seg * 32];
    u32 wds[8];
#pragma unroll
    for (int q = 0; q < 4; ++q) {
      float4 v0 = *reinterpret_cast<const float4*>(src + q * 8);
      float4 v1 = *reinterpret_cast<const float4*>(src + q * 8 + 4);
      int p0 = __builtin_amdgcn_cvt_pk_fp8_f32(v0.x, v0.y, 0, false);
      p0 = __builtin_amdgcn_cvt_pk_fp8_f32(v0.z, v0.w, p0, true);
      int p1 = __builtin_amdgcn_cvt_pk_fp8_f32(v1.x, v1.y, 0, false);
      p1 = __builtin_amdgcn_cvt_pk_fp8_f32(v1.z, v1.w, p1, true);
      wds[q * 2] = (u32)p0;
      wds[q * 2 + 1] = (u32)p1;
    }
    uint4 o0; o0.x = wds[0]; o0.y = wds[1]; o0.z = wds[2]; o0.w = wds[3];
    uint4 o1; o1.x = wds[4]; o1.y = wds[5]; o1.z = wds[6]; o1.w = wds[7];
    *reinterpret_cast<uint4*>(tmpf8 + (size_t)gr * 128 + seg * 32) = o0;
    *reinterpret_cast<uint4*>(tmpf8 + (size_t)gr * 128 + seg * 32 + 16) = o1;
  }
}

// --- gather: 4 nodes per wave over the contiguous combined csr range --------
// nodes 4i..4i+3 share [offs[4i], offs[4i+4]); one ILP-8 pipeline; 3 scalar
// compares route each row into acc bank A/B/C/D (wave-uniform branches).
__global__ __launch_bounds__(256) void k_gather_f8(const u8* __restrict__ tmpf8,
                                                   const int* __restrict__ csr,
                                                   const int* __restrict__ offs,
                                                   const float* __restrict__ dis,
                                                   const float* __restrict__ bias,
                                                   u16* __restrict__ houtb, int n) {
  int node0 = (blockIdx.x * 4 + (threadIdx.x >> 6)) * 4;
  if (node0 >= n) return;
  int lane = threadIdx.x & 63;
  const u16* tp = reinterpret_cast<const u16*>(tmpf8) + lane;  // per-lane base

  int i1 = min(node0 + 1, n), i2 = min(node0 + 2, n);
  int i3 = min(node0 + 3, n), i4 = min(node0 + 4, n);
  int s0 = __builtin_amdgcn_readfirstlane(offs[node0]);
  int m1 = __builtin_amdgcn_readfirstlane(offs[i1]);
  int m2 = __builtin_amdgcn_readfirstlane(offs[i2]);
  int m3 = __builtin_amdgcn_readfirstlane(offs[i3]);
  int s1 = __builtin_amdgcn_readfirstlane(offs[i4]);

  f32x2 aA[2], aB[2], aC[2], aD[2];
#pragma unroll
  for (int i = 0; i < 2; ++i) {
    aA[i] = f32x2{0.f, 0.f}; aB[i] = f32x2{0.f, 0.f};
    aC[i] = f32x2{0.f, 0.f}; aD[i] = f32x2{0.f, 0.f};
  }

  // self-loop rows (issued first, latency overlaps the loop)
  aA[1] += __builtin_amdgcn_cvt_pk_f32_fp8((int)tp[(u32)node0 << 6], false);
  if (node0 + 1 < n)
    aB[1] += __builtin_amdgcn_cvt_pk_f32_fp8((int)tp[(u32)(node0 + 1) << 6], false);
  if (node0 + 2 < n)
    aC[1] += __builtin_amdgcn_cvt_pk_f32_fp8((int)tp[(u32)(node0 + 2) << 6], false);
  if (node0 + 3 < n)
    aD[1] += __builtin_amdgcn_cvt_pk_f32_fp8((int)tp[(u32)(node0 + 3) << 6], false);

  int e = s0;
  for (; e + 7 < s1; e += 8) {
    int ro[8];
#pragma unroll
    for (int j = 0; j < 8; ++j)
      ro[j] = __builtin_amdgcn_readfirstlane(csr[e + j]) << 6;  // u16 elems
    u32 v[8];
#pragma unroll
    for (int j = 0; j < 8; ++j) v[j] = tp[(u32)ro[j]];
#pragma unroll
    for (int j = 0; j < 8; ++j) {
      f32x2 f = __builtin_amdgcn_cvt_pk_f32_fp8((int)v[j], false);
      int pos = e + j;
      if (pos < m1)      aA[j & 1] += f;
      else if (pos < m2) aB[j & 1] += f;
      else if (pos < m3) aC[j & 1] += f;
      else               aD[j & 1] += f;
    }
  }
  for (; e < s1; ++e) {
    int r = __builtin_amdgcn_readfirstlane(csr[e]) << 6;
    f32x2 f = __builtin_amdgcn_cvt_pk_f32_fp8((int)tp[(u32)r], false);
    if (e < m1)      aA[0] += f;
    else if (e < m2) aB[0] += f;
    else if (e < m3) aC[0] += f;
    else             aD[0] += f;
  }

  float2 bb = reinterpret_cast<const float2*>(bias)[lane];
#pragma unroll
  for (int k = 0; k < 4; ++k) {
    int nd = node0 + k;
    if (nd >= n) break;
    f32x2 s = (k == 0) ? (aA[0] + aA[1]) : (k == 1) ? (aB[0] + aB[1])
            : (k == 2) ? (aC[0] + aC[1]) : (aD[0] + aD[1]);
    float dn = dis[nd] * 0.0625f;  // /16 undoes the fp8 pre-scale
    float rx = fmaf(dn, s.x, bb.x);
    float ry = fmaf(dn, s.y, bb.y);
    rx = rx > 0.f ? rx : 0.f;
    ry = ry > 0.f ? ry : 0.f;
    u32 o = (u32)f2bf(rx) | ((u32)f2bf(ry) << 16);
    reinterpret_cast<u32*>(houtb)[(size_t)nd * 64 + lane] = o;
  }
}

// --- mean-pool column sums (bf16 in, fp32 out); 512 blocks -> 65K atomics ---
__global__ __launch_bounds__(256) void k_pool_bf(const u16* __restrict__ h,
                                                 float* __restrict__ pooled, int n) {
  int lane = threadIdx.x & 63, wv = threadIdx.x >> 6;
  const u32* hp = reinterpret_cast<const u32*>(h);
  float sx = 0.f, sy = 0.f;
  for (int r = blockIdx.x * 4 + wv; r < n; r += gridDim.x * 4) {
    u32 u = hp[(size_t)r * 64 + lane];
    sx += bflo(u); sy += bfhi(u);
  }
  __shared__ float red[2][256];
  red[0][threadIdx.x] = sx;
  red[1][threadIdx.x] = sy;
  __syncthreads();
  if (threadIdx.x < 64) {
    float tx = red[0][threadIdx.x] + red[0][threadIdx.x + 64] +
               red[0][threadIdx.x + 128] + red[0][threadIdx.x + 192];
    float ty = red[1][threadIdx.x] + red[1][threadIdx.x + 64] +
               red[1][threadIdx.x + 128] + red[1][threadIdx.x + 192];
    atomicAdd(&pooled[threadIdx.x * 2], tx);
    atomicAdd(&pooled[threadIdx.x * 2 + 1], ty);
  }
}

__global__ void k_final(const float* __restrict__ pooled, const float* __restrict__ Wfc,
                        const float* __restrict__ bfc, float* __restrict__ out,
                        float invn) {
  int j = threadIdx.x;
  if (j < 32) {
    float acc = 0.f;
    for (int k = 0; k < 128; ++k) acc = fmaf(pooled[k], Wfc[k * 32 + j], acc);
    out[j] = fmaf(acc, invn, bfc[j]);
  }
}

extern "C" void kernel_launch(void* const* d_in, const int* in_sizes, int n_in,
                              void* d_out, int out_size, void* d_ws, size_t ws_size,
                              hipStream_t stream) {
  const float* x   = (const float*)d_in[0];
  const int*   ei  = (const int*)d_in[1];
  const float* W0  = (const float*)d_in[2];
  const float* b0  = (const float*)d_in[3];
  const float* W1  = (const float*)d_in[4];
  const float* b1  = (const float*)d_in[5];
  const float* W2  = (const float*)d_in[6];
  const float* b2  = (const float*)d_in[7];
  const float* Wfc = (const float*)d_in[8];
  const float* bfc = (const float*)d_in[9];

  const int n = in_sizes[0] / 128;
  const int e = in_sizes[1] / 2;
  const int nb = (n + (1 << BKSH) - 1) >> BKSH;

  char* ws = (char*)d_ws;
  size_t off = 0;
  auto alloc = [&](size_t bytes) -> void* {
    void* p = ws + off;
    off = (off + bytes + 255) & ~(size_t)255;
    return p;
  };
  int*   mode      = (int*)alloc(sizeof(int));
  int*   bucketCur = (int*)alloc(NBMAX * 4);
  int*   bucketOff = (int*)alloc((NBMAX + 1) * 4);
  int*   offs      = (int*)alloc((size_t)(n + 1) * 4);
  float* dis       = (float*)alloc((size_t)n * 4);
  int*   csr       = (int*)alloc((size_t)e * 4);
  float* pooled    = (float*)alloc(128 * 4);
  u16*   wp        = (u16*)alloc(3 * 2048 * 8 * 2);
  u8*    tmpf8     = (u8*)alloc((size_t)n * 128);
  u16*   houtb     = (u16*)alloc((size_t)n * 128 * 2);
  int*   pairBuf   = (int*)houtb;  // alias: padded pairs (nb*CAP*8B <= 25.2MB)
                                   // consumed by b_fine before gather0 writes

  k_init<<<2, 256, 0, stream>>>(ei, mode, bucketCur, pooled, e, nb);
  b_scatter<<<(e + SCH - 1) / SCH, 256, 0, stream>>>(ei, mode, bucketCur, pairBuf, e, nb);
  b_bscan2<<<1, 256, 0, stream>>>(bucketCur, bucketOff, nb);
  b_fine<<<nb, 512, 0, stream>>>(pairBuf, bucketCur, bucketOff, offs, dis, csr, n, e);

  k_wpack3<<<24, 256, 0, stream>>>(W0, W1, W2, wp);

  int gg = (n + 63) / 64;
  int gn = (n + 15) / 16;

  // layer 0 (reads fp32 x directly)
  k_gemm_mfma<true><<<gg, 256, 0, stream>>>(x, wp, dis, tmpf8, n);
  k_gather_f8<<<gn, 256, 0, stream>>>(tmpf8, csr, offs, dis, b0, houtb, n);
  // layer 1
  k_gemm_mfma<false><<<gg, 256, 0, stream>>>(houtb, wp + 2048 * 8, dis, tmpf8, n);
  k_gather_f8<<<gn, 256, 0, stream>>>(tmpf8, csr, offs, dis, b1, houtb, n);
  // layer 2
  k_gemm_mfma<false><<<gg, 256, 0, stream>>>(houtb, wp + 2 * 2048 * 8, dis, tmpf8, n);
  k_gather_f8<<<gn, 256, 0, stream>>>(tmpf8, csr, offs, dis, b2, houtb, n);

  k_pool_bf<<<512, 256, 0, stream>>>(houtb, pooled, n);
  k_final<<<1, 32, 0, stream>>>(pooled, Wfc, bfc, (float*)d_out, 1.0f / (float)n);
}

// Round 14
// 325.074 us; speedup vs baseline: 1.4773x; 1.4773x over previous
//
#include <hip/hip_runtime.h>
#include <hip/hip_bf16.h>
#include <cstdint>

// ---------------------------------------------------------------------------
// GCN 3-layer forward, bf16 pipeline + MFMA GEMM + fp8 gather operand.
// R14: recombine best-measured parts. Gather = R12's 2-node/wave (59.2us
//      proven; R13's 4-node branch-tree routing doubled VALU work and halved
//      occupancy -> reverted). Build = R13's padded-bucket scatter (no
//      b_count pass, -26us proven). No other changes.
// ---------------------------------------------------------------------------

typedef unsigned short u16;
typedef unsigned int u32;
typedef unsigned char u8;
typedef __attribute__((ext_vector_type(8))) short short8v;
typedef __attribute__((ext_vector_type(4))) float f32x4;
typedef __attribute__((ext_vector_type(2))) float f32x2;

#define NBMAX 256
#define BKSH  9
#define SCH   2048
#define CAP   12288   // padded pair slots per bucket

__device__ inline u16 f2bf(float f) {
  u32 u = __float_as_uint(f);
  u += 0x7fff + ((u >> 16) & 1);  // RNE
  return (u16)(u >> 16);
}
__device__ inline float bflo(u32 u) { return __uint_as_float(u << 16); }
__device__ inline float bfhi(u32 u) { return __uint_as_float(u & 0xffff0000u); }

// --- init: block 0 detects edge dtype, block 1 zeros cursors/pooled ---------
__global__ void k_init(const int* __restrict__ ei, int* __restrict__ mode,
                       int* __restrict__ bucketCur, float* __restrict__ pooled,
                       int e, int nb) {
  if (blockIdx.x == 0) {
    __shared__ int any;
    if (threadIdx.x == 0) any = 0;
    __syncthreads();
    int lim = min(e, 2048);
    int local = 0;
    for (int i = threadIdx.x; i < lim; i += blockDim.x)
      local |= (ei[2 * i + 1] != 0);
    if (local) atomicOr(&any, 1);
    __syncthreads();
    if (threadIdx.x == 0) mode[0] = (any == 0) ? 1 : 0;
  } else {
    int i = threadIdx.x;
    if (i < nb) bucketCur[i] = 0;
    if (i < 128) pooled[i] = 0.0f;
  }
}

// --- scatter (src,dst) into PADDED bucket regions, atomic cursors -----------
__global__ __launch_bounds__(256) void b_scatter(const int* __restrict__ ei,
                                                 const int* __restrict__ mode,
                                                 int* __restrict__ bucketCur,
                                                 int* __restrict__ pairBuf,
                                                 int e, int nb) {
  __shared__ int cnt[NBMAX];
  __shared__ int pre[NBMAX];
  __shared__ int base[NBMAX];
  __shared__ int stage[2 * SCH];
  const int t = threadIdx.x;
  const int chunk0 = blockIdx.x * SCH;
  const int nloc = min(SCH, e - chunk0);
  const int m = mode[0];

  cnt[t] = 0;
  __syncthreads();

  int myS[SCH / 256], myD[SCH / 256], myB[SCH / 256], mySlot[SCH / 256];
#pragma unroll
  for (int j = 0; j < SCH / 256; ++j) {
    int li = j * 256 + t;
    myB[j] = -1;
    if (li < nloc) {
      int i = chunk0 + li;
      long long di = (long long)e + i;
      int s = m ? ei[2 * (long long)i] : ei[i];
      int d = m ? ei[2 * di] : ei[di];
      int b = d >> BKSH;
      myS[j] = s; myD[j] = d; myB[j] = b;
      mySlot[j] = atomicAdd(&cnt[b], 1);
    }
  }
  __syncthreads();

  int c0 = cnt[t];
  pre[t] = c0;
  __syncthreads();
  for (int d = 1; d < NBMAX; d <<= 1) {
    int v = (t >= d) ? pre[t - d] : 0;
    __syncthreads();
    pre[t] += v;
    __syncthreads();
  }
  int myPre = pre[t] - c0;
  if (t < nb && c0 > 0) base[t] = atomicAdd(&bucketCur[t], c0);  // bucket-rel
  __syncthreads();
  cnt[t] = myPre;
  __syncthreads();

#pragma unroll
  for (int j = 0; j < SCH / 256; ++j) {
    if (myB[j] >= 0) {
      int si = cnt[myB[j]] + mySlot[j];
      stage[2 * si] = myS[j];
      stage[2 * si + 1] = myD[j];
    }
  }
  __syncthreads();

  int wave = t >> 6, lane = t & 63;
  for (int b = wave; b < nb; b += 4) {
    int cb = pre[b] - cnt[b];
    if (cb <= 0) continue;
    int lo = cnt[b];
    int gb = base[b];
    int room = CAP - gb;
    int allowed = (room > 0) ? min(cb, room) : 0;  // overflow guard (impossible)
    size_t dst = ((size_t)b * CAP + gb) * 2;
    for (int j = lane; j < 2 * allowed; j += 64)
      pairBuf[dst + j] = stage[2 * lo + j];
  }
}

// --- tiny scan of bucket counts -> global csr base per bucket ---------------
__global__ __launch_bounds__(256) void b_bscan2(const int* __restrict__ bucketCur,
                                                int* __restrict__ bucketOff, int nb) {
  __shared__ int sh[NBMAX];
  int t = threadIdx.x;
  int c = (t < nb) ? bucketCur[t] : 0;
  sh[t] = c;
  __syncthreads();
  for (int d = 1; d < NBMAX; d <<= 1) {
    int v = (t >= d) ? sh[t - d] : 0;
    __syncthreads();
    sh[t] += v;
    __syncthreads();
  }
  if (t < nb) bucketOff[t] = sh[t] - c;  // exclusive
}

// --- per-bucket fine CSR from padded pairs -> contiguous offs/dis/csr -------
__global__ __launch_bounds__(512) void b_fine(const int* __restrict__ pairBuf,
                                              const int* __restrict__ bucketCur,
                                              const int* __restrict__ bucketOff,
                                              int* __restrict__ offs,
                                              float* __restrict__ dis,
                                              int* __restrict__ csr,
                                              int n, int e) {
  const int b = blockIdx.x;
  const int d0 = b << BKSH;
  const size_t pb = (size_t)b * CAP;
  const int cnt = bucketCur[b];
  const int lo = bucketOff[b];
  __shared__ int arr[1 << BKSH];
  __shared__ int cur[1 << BKSH];
  const int t = threadIdx.x;
  arr[t] = 0; cur[t] = 0;
  __syncthreads();
  for (int i = t; i < cnt; i += 512) {
    int d = pairBuf[2 * (pb + i) + 1];
    atomicAdd(&arr[d - d0], 1);
  }
  __syncthreads();
  int c0 = arr[t];
  __syncthreads();
  for (int dd = 1; dd < 512; dd <<= 1) {
    int v = (t >= dd) ? arr[t - dd] : 0;
    __syncthreads();
    arr[t] += v;
    __syncthreads();
  }
  int epre = arr[t] - c0;
  int gd = d0 + t;
  if (gd < n) {
    offs[gd] = lo + epre;
    dis[gd] = rsqrtf((float)c0 + 1.0f);
  }
  __syncthreads();
  arr[t] = epre;
  __syncthreads();
  for (int i = t; i < cnt; i += 512) {
    int s = pairBuf[2 * (pb + i)];
    int d = pairBuf[2 * (pb + i) + 1];
    int ld = d - d0;
    int p = lo + arr[ld] + atomicAdd(&cur[ld], 1);
    csr[p] = s;
  }
  if (b == 0 && t == 0) offs[n] = e;
}

// --- pack all 3 weights fp32 -> MFMA B-fragments bf16 (grid 24) -------------
__global__ __launch_bounds__(256) void k_wpack3(const float* __restrict__ W0,
                                                const float* __restrict__ W1,
                                                const float* __restrict__ W2,
                                                u16* __restrict__ wp) {
  int f = blockIdx.x * 256 + threadIdx.x;
  int wsel = f >> 11;
  int li = f & 2047;
  const float* W = (wsel == 0) ? W0 : (wsel == 1) ? W1 : W2;
  u16* dst = wp + (size_t)wsel * 2048 * 8;
  int ct = li >> 8, kc = (li >> 6) & 3, lane = li & 63;
  int g = lane >> 4, c = lane & 15;
  u32 o[4];
#pragma unroll
  for (int q = 0; q < 4; ++q) {
    int k = kc * 32 + g * 8 + q * 2;
    u16 e0 = f2bf(W[(size_t)k * 128 + ct * 16 + c]);
    u16 e1 = f2bf(W[(size_t)(k + 1) * 128 + ct * 16 + c]);
    o[q] = (u32)e0 | ((u32)e1 << 16);
  }
  uint4 v; v.x = o[0]; v.y = o[1]; v.z = o[2]; v.w = o[3];
  *reinterpret_cast<uint4*>(dst + (size_t)li * 8) = v;
}

// --- GEMM: tmp[r,:] = fp8( 16 * dis[r] * (h[r,:] @ W) ) via MFMA ------------
template <bool FP32IN>
__global__ __launch_bounds__(256) void k_gemm_mfma(const void* __restrict__ hin,
                                                   const u16* __restrict__ wp,
                                                   const float* __restrict__ dis,
                                                   u8* __restrict__ tmpf8, int n) {
  __shared__ float eps[64 * 132];
  const int tid = threadIdx.x;
  const int w = tid >> 6, l = tid & 63;
  const int g = l >> 4, c16 = l & 15;
  const int rowbase = blockIdx.x * 64 + w * 16;

  const short8v zero8 = {0, 0, 0, 0, 0, 0, 0, 0};
  short8v a[4];
  int ar = rowbase + c16;
  bool aok = ar < n;
#pragma unroll
  for (int kc = 0; kc < 4; ++kc) {
    if (FP32IN) {
      const float* hrow = (const float*)hin + (size_t)ar * 128;
      short8v s = zero8;
      if (aok) {
        float4 v0 = *reinterpret_cast<const float4*>(hrow + kc * 32 + g * 8);
        float4 v1 = *reinterpret_cast<const float4*>(hrow + kc * 32 + g * 8 + 4);
        s[0] = (short)f2bf(v0.x); s[1] = (short)f2bf(v0.y);
        s[2] = (short)f2bf(v0.z); s[3] = (short)f2bf(v0.w);
        s[4] = (short)f2bf(v1.x); s[5] = (short)f2bf(v1.y);
        s[6] = (short)f2bf(v1.z); s[7] = (short)f2bf(v1.w);
      }
      a[kc] = s;
    } else {
      const u16* hrow = (const u16*)hin + (size_t)ar * 128;
      a[kc] = aok ? *reinterpret_cast<const short8v*>(hrow + kc * 32 + g * 8) : zero8;
    }
  }

  f32x4 acc[8];
#pragma unroll
  for (int ct = 0; ct < 8; ++ct) acc[ct] = f32x4{0.f, 0.f, 0.f, 0.f};

#pragma unroll
  for (int ct = 0; ct < 8; ++ct) {
#pragma unroll
    for (int kc = 0; kc < 4; ++kc) {
      short8v b = *reinterpret_cast<const short8v*>(wp + ((size_t)(ct * 4 + kc) * 64 + l) * 8);
      acc[ct] = __builtin_amdgcn_mfma_f32_16x16x32_bf16(a[kc], b, acc[ct], 0, 0, 0);
    }
  }

  // scale by 16*dis[row] (x16 clears fp8 subnormal region; gather divides out)
#pragma unroll
  for (int j = 0; j < 4; ++j) {
    int rl = w * 16 + g * 4 + j;
    int gr = blockIdx.x * 64 + rl;
    float dn = (gr < n) ? dis[gr] * 16.0f : 0.f;
#pragma unroll
    for (int ct = 0; ct < 8; ++ct)
      eps[rl * 132 + ct * 16 + c16] = acc[ct][j] * dn;
  }
  __syncthreads();

  // readback: thread -> (row rl, 32-col segment), pack fp8 and store 32B
  int rl = tid >> 2, seg = tid & 3;
  int gr = blockIdx.x * 64 + rl;
  if (gr < n) {
    const float* src = &eps[rl * 132 + seg * 32];
    u32 wds[8];
#pragma unroll
    for (int q = 0; q < 4; ++q) {
      float4 v0 = *reinterpret_cast<const float4*>(src + q * 8);
      float4 v1 = *reinterpret_cast<const float4*>(src + q * 8 + 4);
      int p0 = __builtin_amdgcn_cvt_pk_fp8_f32(v0.x, v0.y, 0, false);
      p0 = __builtin_amdgcn_cvt_pk_fp8_f32(v0.z, v0.w, p0, true);
      int p1 = __builtin_amdgcn_cvt_pk_fp8_f32(v1.x, v1.y, 0, false);
      p1 = __builtin_amdgcn_cvt_pk_fp8_f32(v1.z, v1.w, p1, true);
      wds[q * 2] = (u32)p0;
      wds[q * 2 + 1] = (u32)p1;
    }
    uint4 o0; o0.x = wds[0]; o0.y = wds[1]; o0.z = wds[2]; o0.w = wds[3];
    uint4 o1; o1.x = wds[4]; o1.y = wds[5]; o1.z = wds[6]; o1.w = wds[7];
    *reinterpret_cast<uint4*>(tmpf8 + (size_t)gr * 128 + seg * 32) = o0;
    *reinterpret_cast<uint4*>(tmpf8 + (size_t)gr * 128 + seg * 32 + 16) = o1;
  }
}

// --- gather: 2 nodes per wave over the contiguous combined csr range --------
// nodes (2i,2i+1) share range [offs[2i], offs[2i+2]); one ILP-8 pipeline,
// scalar compare vs mid routes into acc bank A/B (R12-proven, 59.2us).
__global__ __launch_bounds__(256) void k_gather_f8(const u8* __restrict__ tmpf8,
                                                   const int* __restrict__ csr,
                                                   const int* __restrict__ offs,
                                                   const float* __restrict__ dis,
                                                   const float* __restrict__ bias,
                                                   u16* __restrict__ houtb, int n) {
  int node0 = blockIdx.x * 8 + (threadIdx.x >> 6) * 2;
  if (node0 >= n) return;
  int node1 = node0 + 1;
  bool has1 = node1 < n;
  int lane = threadIdx.x & 63;
  const u16* tp = reinterpret_cast<const u16*>(tmpf8) + lane;  // per-lane base

  int s0  = __builtin_amdgcn_readfirstlane(offs[node0]);
  int mid = __builtin_amdgcn_readfirstlane(offs[node1]);
  int s1  = has1 ? __builtin_amdgcn_readfirstlane(offs[node1 + 1]) : mid;

  f32x2 accA[4], accB[4];
#pragma unroll
  for (int i = 0; i < 4; ++i) { accA[i] = f32x2{0.f, 0.f}; accB[i] = f32x2{0.f, 0.f}; }

  // self-loop rows (issued first, latency overlaps the loop)
  accA[1] += __builtin_amdgcn_cvt_pk_f32_fp8((int)tp[(u32)node0 << 6], false);
  if (has1)
    accB[1] += __builtin_amdgcn_cvt_pk_f32_fp8((int)tp[(u32)node1 << 6], false);

  int e = s0;
  for (; e + 7 < s1; e += 8) {
    int ro[8];
#pragma unroll
    for (int j = 0; j < 8; ++j)
      ro[j] = __builtin_amdgcn_readfirstlane(csr[e + j]) << 6;  // u16 elems
    u32 v[8];
#pragma unroll
    for (int j = 0; j < 8; ++j) v[j] = tp[(u32)ro[j]];
#pragma unroll
    for (int j = 0; j < 8; ++j) {
      f32x2 f = __builtin_amdgcn_cvt_pk_f32_fp8((int)v[j], false);
      if (e + j < mid) accA[j & 3] += f; else accB[j & 3] += f;
    }
  }
  for (; e < s1; ++e) {
    int r = __builtin_amdgcn_readfirstlane(csr[e]) << 6;
    f32x2 f = __builtin_amdgcn_cvt_pk_f32_fp8((int)tp[(u32)r], false);
    if (e < mid) accA[0] += f; else accB[0] += f;
  }

  float2 bb = reinterpret_cast<const float2*>(bias)[lane];
  {
    f32x2 s = (accA[0] + accA[1]) + (accA[2] + accA[3]);
    float dn = dis[node0] * 0.0625f;
    float rx = fmaf(dn, s.x, bb.x);
    float ry = fmaf(dn, s.y, bb.y);
    rx = rx > 0.f ? rx : 0.f;
    ry = ry > 0.f ? ry : 0.f;
    u32 o = (u32)f2bf(rx) | ((u32)f2bf(ry) << 16);
    reinterpret_cast<u32*>(houtb)[(size_t)node0 * 64 + lane] = o;
  }
  if (has1) {
    f32x2 s = (accB[0] + accB[1]) + (accB[2] + accB[3]);
    float dn = dis[node1] * 0.0625f;
    float rx = fmaf(dn, s.x, bb.x);
    float ry = fmaf(dn, s.y, bb.y);
    rx = rx > 0.f ? rx : 0.f;
    ry = ry > 0.f ? ry : 0.f;
    u32 o = (u32)f2bf(rx) | ((u32)f2bf(ry) << 16);
    reinterpret_cast<u32*>(houtb)[(size_t)node1 * 64 + lane] = o;
  }
}

// --- mean-pool column sums (bf16 in, fp32 out); 512 blocks -> 65K atomics ---
__global__ __launch_bounds__(256) void k_pool_bf(const u16* __restrict__ h,
                                                 float* __restrict__ pooled, int n) {
  int lane = threadIdx.x & 63, wv = threadIdx.x >> 6;
  const u32* hp = reinterpret_cast<const u32*>(h);
  float sx = 0.f, sy = 0.f;
  for (int r = blockIdx.x * 4 + wv; r < n; r += gridDim.x * 4) {
    u32 u = hp[(size_t)r * 64 + lane];
    sx += bflo(u); sy += bfhi(u);
  }
  __shared__ float red[2][256];
  red[0][threadIdx.x] = sx;
  red[1][threadIdx.x] = sy;
  __syncthreads();
  if (threadIdx.x < 64) {
    float tx = red[0][threadIdx.x] + red[0][threadIdx.x + 64] +
               red[0][threadIdx.x + 128] + red[0][threadIdx.x + 192];
    float ty = red[1][threadIdx.x] + red[1][threadIdx.x + 64] +
               red[1][threadIdx.x + 128] + red[1][threadIdx.x + 192];
    atomicAdd(&pooled[threadIdx.x * 2], tx);
    atomicAdd(&pooled[threadIdx.x * 2 + 1], ty);
  }
}

__global__ void k_final(const float* __restrict__ pooled, const float* __restrict__ Wfc,
                        const float* __restrict__ bfc, float* __restrict__ out,
                        float invn) {
  int j = threadIdx.x;
  if (j < 32) {
    float acc = 0.f;
    for (int k = 0; k < 128; ++k) acc = fmaf(pooled[k], Wfc[k * 32 + j], acc);
    out[j] = fmaf(acc, invn, bfc[j]);
  }
}

extern "C" void kernel_launch(void* const* d_in, const int* in_sizes, int n_in,
                              void* d_out, int out_size, void* d_ws, size_t ws_size,
                              hipStream_t stream) {
  const float* x   = (const float*)d_in[0];
  const int*   ei  = (const int*)d_in[1];
  const float* W0  = (const float*)d_in[2];
  const float* b0  = (const float*)d_in[3];
  const float* W1  = (const float*)d_in[4];
  const float* b1  = (const float*)d_in[5];
  const float* W2  = (const float*)d_in[6];
  const float* b2  = (const float*)d_in[7];
  const float* Wfc = (const float*)d_in[8];
  const float* bfc = (const float*)d_in[9];

  const int n = in_sizes[0] / 128;
  const int e = in_sizes[1] / 2;
  const int nb = (n + (1 << BKSH) - 1) >> BKSH;

  char* ws = (char*)d_ws;
  size_t off = 0;
  auto alloc = [&](size_t bytes) -> void* {
    void* p = ws + off;
    off = (off + bytes + 255) & ~(size_t)255;
    return p;
  };
  int*   mode      = (int*)alloc(sizeof(int));
  int*   bucketCur = (int*)alloc(NBMAX * 4);
  int*   bucketOff = (int*)alloc((NBMAX + 1) * 4);
  int*   offs      = (int*)alloc((size_t)(n + 1) * 4);
  float* dis       = (float*)alloc((size_t)n * 4);
  int*   csr       = (int*)alloc((size_t)e * 4);
  float* pooled    = (float*)alloc(128 * 4);
  u16*   wp        = (u16*)alloc(3 * 2048 * 8 * 2);
  u8*    tmpf8     = (u8*)alloc((size_t)n * 128);
  u16*   houtb     = (u16*)alloc((size_t)n * 128 * 2);
  int*   pairBuf   = (int*)houtb;  // alias: padded pairs (nb*CAP*8B <= 25.2MB)
                                   // consumed by b_fine before gather0 writes

  k_init<<<2, 256, 0, stream>>>(ei, mode, bucketCur, pooled, e, nb);
  b_scatter<<<(e + SCH - 1) / SCH, 256, 0, stream>>>(ei, mode, bucketCur, pairBuf, e, nb);
  b_bscan2<<<1, 256, 0, stream>>>(bucketCur, bucketOff, nb);
  b_fine<<<nb, 512, 0, stream>>>(pairBuf, bucketCur, bucketOff, offs, dis, csr, n, e);

  k_wpack3<<<24, 256, 0, stream>>>(W0, W1, W2, wp);

  int gg = (n + 63) / 64;
  int gn = (n + 7) / 8;

  // layer 0 (reads fp32 x directly)
  k_gemm_mfma<true><<<gg, 256, 0, stream>>>(x, wp, dis, tmpf8, n);
  k_gather_f8<<<gn, 256, 0, stream>>>(tmpf8, csr, offs, dis, b0, houtb, n);
  // layer 1
  k_gemm_mfma<false><<<gg, 256, 0, stream>>>(houtb, wp + 2048 * 8, dis, tmpf8, n);
  k_gather_f8<<<gn, 256, 0, stream>>>(tmpf8, csr, offs, dis, b1, houtb, n);
  // layer 2
  k_gemm_mfma<false><<<gg, 256, 0, stream>>>(houtb, wp + 2 * 2048 * 8, dis, tmpf8, n);
  k_gather_f8<<<gn, 256, 0, stream>>>(tmpf8, csr, offs, dis, b2, houtb, n);

  k_pool_bf<<<512, 256, 0, stream>>>(houtb, pooled, n);
  k_final<<<1, 32, 0, stream>>>(pooled, Wfc, bfc, (float*)d_out, 1.0f / (float)n);
}

// Round 15
// 292.115 us; speedup vs baseline: 1.6440x; 1.1128x over previous
//
#include <hip/hip_runtime.h>
#include <hip/hip_bf16.h>
#include <cstdint>

// ---------------------------------------------------------------------------
// GCN 3-layer forward, bf16 pipeline + MFMA GEMM + fp8 gather operand.
// R15: gather packs TWO rows per VMEM instruction: half-wave h loads node_h's
//      edge row as u32x32 (=full 128B fp8 row); each half processes its own
//      node's csr range (no routing compares, no cross-lane combine).
//      VMEM instrs/edge 1 -> 0.5 (R10-R12 evidence: cost is per-instruction,
//      not bytes/lines/VALU). Predicated tail (no remainder loop).
//      Everything else identical to R14.
// ---------------------------------------------------------------------------

typedef unsigned short u16;
typedef unsigned int u32;
typedef unsigned char u8;
typedef __attribute__((ext_vector_type(8))) short short8v;
typedef __attribute__((ext_vector_type(4))) float f32x4;
typedef __attribute__((ext_vector_type(2))) float f32x2;

#define NBMAX 256
#define BKSH  9
#define SCH   2048
#define CAP   12288   // padded pair slots per bucket

__device__ inline u16 f2bf(float f) {
  u32 u = __float_as_uint(f);
  u += 0x7fff + ((u >> 16) & 1);  // RNE
  return (u16)(u >> 16);
}
__device__ inline float bflo(u32 u) { return __uint_as_float(u << 16); }
__device__ inline float bfhi(u32 u) { return __uint_as_float(u & 0xffff0000u); }

// --- init: block 0 detects edge dtype, block 1 zeros cursors/pooled ---------
__global__ void k_init(const int* __restrict__ ei, int* __restrict__ mode,
                       int* __restrict__ bucketCur, float* __restrict__ pooled,
                       int e, int nb) {
  if (blockIdx.x == 0) {
    __shared__ int any;
    if (threadIdx.x == 0) any = 0;
    __syncthreads();
    int lim = min(e, 2048);
    int local = 0;
    for (int i = threadIdx.x; i < lim; i += blockDim.x)
      local |= (ei[2 * i + 1] != 0);
    if (local) atomicOr(&any, 1);
    __syncthreads();
    if (threadIdx.x == 0) mode[0] = (any == 0) ? 1 : 0;
  } else {
    int i = threadIdx.x;
    if (i < nb) bucketCur[i] = 0;
    if (i < 128) pooled[i] = 0.0f;
  }
}

// --- scatter (src,dst) into PADDED bucket regions, atomic cursors -----------
__global__ __launch_bounds__(256) void b_scatter(const int* __restrict__ ei,
                                                 const int* __restrict__ mode,
                                                 int* __restrict__ bucketCur,
                                                 int* __restrict__ pairBuf,
                                                 int e, int nb) {
  __shared__ int cnt[NBMAX];
  __shared__ int pre[NBMAX];
  __shared__ int base[NBMAX];
  __shared__ int stage[2 * SCH];
  const int t = threadIdx.x;
  const int chunk0 = blockIdx.x * SCH;
  const int nloc = min(SCH, e - chunk0);
  const int m = mode[0];

  cnt[t] = 0;
  __syncthreads();

  int myS[SCH / 256], myD[SCH / 256], myB[SCH / 256], mySlot[SCH / 256];
#pragma unroll
  for (int j = 0; j < SCH / 256; ++j) {
    int li = j * 256 + t;
    myB[j] = -1;
    if (li < nloc) {
      int i = chunk0 + li;
      long long di = (long long)e + i;
      int s = m ? ei[2 * (long long)i] : ei[i];
      int d = m ? ei[2 * di] : ei[di];
      int b = d >> BKSH;
      myS[j] = s; myD[j] = d; myB[j] = b;
      mySlot[j] = atomicAdd(&cnt[b], 1);
    }
  }
  __syncthreads();

  int c0 = cnt[t];
  pre[t] = c0;
  __syncthreads();
  for (int d = 1; d < NBMAX; d <<= 1) {
    int v = (t >= d) ? pre[t - d] : 0;
    __syncthreads();
    pre[t] += v;
    __syncthreads();
  }
  int myPre = pre[t] - c0;
  if (t < nb && c0 > 0) base[t] = atomicAdd(&bucketCur[t], c0);  // bucket-rel
  __syncthreads();
  cnt[t] = myPre;
  __syncthreads();

#pragma unroll
  for (int j = 0; j < SCH / 256; ++j) {
    if (myB[j] >= 0) {
      int si = cnt[myB[j]] + mySlot[j];
      stage[2 * si] = myS[j];
      stage[2 * si + 1] = myD[j];
    }
  }
  __syncthreads();

  int wave = t >> 6, lane = t & 63;
  for (int b = wave; b < nb; b += 4) {
    int cb = pre[b] - cnt[b];
    if (cb <= 0) continue;
    int lo = cnt[b];
    int gb = base[b];
    int room = CAP - gb;
    int allowed = (room > 0) ? min(cb, room) : 0;  // overflow guard (impossible)
    size_t dst = ((size_t)b * CAP + gb) * 2;
    for (int j = lane; j < 2 * allowed; j += 64)
      pairBuf[dst + j] = stage[2 * lo + j];
  }
}

// --- tiny scan of bucket counts -> global csr base per bucket ---------------
__global__ __launch_bounds__(256) void b_bscan2(const int* __restrict__ bucketCur,
                                                int* __restrict__ bucketOff, int nb) {
  __shared__ int sh[NBMAX];
  int t = threadIdx.x;
  int c = (t < nb) ? bucketCur[t] : 0;
  sh[t] = c;
  __syncthreads();
  for (int d = 1; d < NBMAX; d <<= 1) {
    int v = (t >= d) ? sh[t - d] : 0;
    __syncthreads();
    sh[t] += v;
    __syncthreads();
  }
  if (t < nb) bucketOff[t] = sh[t] - c;  // exclusive
}

// --- per-bucket fine CSR from padded pairs -> contiguous offs/dis/csr -------
__global__ __launch_bounds__(512) void b_fine(const int* __restrict__ pairBuf,
                                              const int* __restrict__ bucketCur,
                                              const int* __restrict__ bucketOff,
                                              int* __restrict__ offs,
                                              float* __restrict__ dis,
                                              int* __restrict__ csr,
                                              int n, int e) {
  const int b = blockIdx.x;
  const int d0 = b << BKSH;
  const size_t pb = (size_t)b * CAP;
  const int cnt = bucketCur[b];
  const int lo = bucketOff[b];
  __shared__ int arr[1 << BKSH];
  __shared__ int cur[1 << BKSH];
  const int t = threadIdx.x;
  arr[t] = 0; cur[t] = 0;
  __syncthreads();
  for (int i = t; i < cnt; i += 512) {
    int d = pairBuf[2 * (pb + i) + 1];
    atomicAdd(&arr[d - d0], 1);
  }
  __syncthreads();
  int c0 = arr[t];
  __syncthreads();
  for (int dd = 1; dd < 512; dd <<= 1) {
    int v = (t >= dd) ? arr[t - dd] : 0;
    __syncthreads();
    arr[t] += v;
    __syncthreads();
  }
  int epre = arr[t] - c0;
  int gd = d0 + t;
  if (gd < n) {
    offs[gd] = lo + epre;
    dis[gd] = rsqrtf((float)c0 + 1.0f);
  }
  __syncthreads();
  arr[t] = epre;
  __syncthreads();
  for (int i = t; i < cnt; i += 512) {
    int s = pairBuf[2 * (pb + i)];
    int d = pairBuf[2 * (pb + i) + 1];
    int ld = d - d0;
    int p = lo + arr[ld] + atomicAdd(&cur[ld], 1);
    csr[p] = s;
  }
  if (b == 0 && t == 0) offs[n] = e;
}

// --- pack all 3 weights fp32 -> MFMA B-fragments bf16 (grid 24) -------------
__global__ __launch_bounds__(256) void k_wpack3(const float* __restrict__ W0,
                                                const float* __restrict__ W1,
                                                const float* __restrict__ W2,
                                                u16* __restrict__ wp) {
  int f = blockIdx.x * 256 + threadIdx.x;
  int wsel = f >> 11;
  int li = f & 2047;
  const float* W = (wsel == 0) ? W0 : (wsel == 1) ? W1 : W2;
  u16* dst = wp + (size_t)wsel * 2048 * 8;
  int ct = li >> 8, kc = (li >> 6) & 3, lane = li & 63;
  int g = lane >> 4, c = lane & 15;
  u32 o[4];
#pragma unroll
  for (int q = 0; q < 4; ++q) {
    int k = kc * 32 + g * 8 + q * 2;
    u16 e0 = f2bf(W[(size_t)k * 128 + ct * 16 + c]);
    u16 e1 = f2bf(W[(size_t)(k + 1) * 128 + ct * 16 + c]);
    o[q] = (u32)e0 | ((u32)e1 << 16);
  }
  uint4 v; v.x = o[0]; v.y = o[1]; v.z = o[2]; v.w = o[3];
  *reinterpret_cast<uint4*>(dst + (size_t)li * 8) = v;
}

// --- GEMM: tmp[r,:] = fp8( 16 * dis[r] * (h[r,:] @ W) ) via MFMA ------------
template <bool FP32IN>
__global__ __launch_bounds__(256) void k_gemm_mfma(const void* __restrict__ hin,
                                                   const u16* __restrict__ wp,
                                                   const float* __restrict__ dis,
                                                   u8* __restrict__ tmpf8, int n) {
  __shared__ float eps[64 * 132];
  const int tid = threadIdx.x;
  const int w = tid >> 6, l = tid & 63;
  const int g = l >> 4, c16 = l & 15;
  const int rowbase = blockIdx.x * 64 + w * 16;

  const short8v zero8 = {0, 0, 0, 0, 0, 0, 0, 0};
  short8v a[4];
  int ar = rowbase + c16;
  bool aok = ar < n;
#pragma unroll
  for (int kc = 0; kc < 4; ++kc) {
    if (FP32IN) {
      const float* hrow = (const float*)hin + (size_t)ar * 128;
      short8v s = zero8;
      if (aok) {
        float4 v0 = *reinterpret_cast<const float4*>(hrow + kc * 32 + g * 8);
        float4 v1 = *reinterpret_cast<const float4*>(hrow + kc * 32 + g * 8 + 4);
        s[0] = (short)f2bf(v0.x); s[1] = (short)f2bf(v0.y);
        s[2] = (short)f2bf(v0.z); s[3] = (short)f2bf(v0.w);
        s[4] = (short)f2bf(v1.x); s[5] = (short)f2bf(v1.y);
        s[6] = (short)f2bf(v1.z); s[7] = (short)f2bf(v1.w);
      }
      a[kc] = s;
    } else {
      const u16* hrow = (const u16*)hin + (size_t)ar * 128;
      a[kc] = aok ? *reinterpret_cast<const short8v*>(hrow + kc * 32 + g * 8) : zero8;
    }
  }

  f32x4 acc[8];
#pragma unroll
  for (int ct = 0; ct < 8; ++ct) acc[ct] = f32x4{0.f, 0.f, 0.f, 0.f};

#pragma unroll
  for (int ct = 0; ct < 8; ++ct) {
#pragma unroll
    for (int kc = 0; kc < 4; ++kc) {
      short8v b = *reinterpret_cast<const short8v*>(wp + ((size_t)(ct * 4 + kc) * 64 + l) * 8);
      acc[ct] = __builtin_amdgcn_mfma_f32_16x16x32_bf16(a[kc], b, acc[ct], 0, 0, 0);
    }
  }

  // scale by 16*dis[row] (x16 clears fp8 subnormal region; gather divides out)
#pragma unroll
  for (int j = 0; j < 4; ++j) {
    int rl = w * 16 + g * 4 + j;
    int gr = blockIdx.x * 64 + rl;
    float dn = (gr < n) ? dis[gr] * 16.0f : 0.f;
#pragma unroll
    for (int ct = 0; ct < 8; ++ct)
      eps[rl * 132 + ct * 16 + c16] = acc[ct][j] * dn;
  }
  __syncthreads();

  // readback: thread -> (row rl, 32-col segment), pack fp8 and store 32B
  int rl = tid >> 2, seg = tid & 3;
  int gr = blockIdx.x * 64 + rl;
  if (gr < n) {
    const float* src = &eps[rl * 132 + seg * 32];
    u32 wds[8];
#pragma unroll
    for (int q = 0; q < 4; ++q) {
      float4 v0 = *reinterpret_cast<const float4*>(src + q * 8);
      float4 v1 = *reinterpret_cast<const float4*>(src + q * 8 + 4);
      int p0 = __builtin_amdgcn_cvt_pk_fp8_f32(v0.x, v0.y, 0, false);
      p0 = __builtin_amdgcn_cvt_pk_fp8_f32(v0.z, v0.w, p0, true);
      int p1 = __builtin_amdgcn_cvt_pk_fp8_f32(v1.x, v1.y, 0, false);
      p1 = __builtin_amdgcn_cvt_pk_fp8_f32(v1.z, v1.w, p1, true);
      wds[q * 2] = (u32)p0;
      wds[q * 2 + 1] = (u32)p1;
    }
    uint4 o0; o0.x = wds[0]; o0.y = wds[1]; o0.z = wds[2]; o0.w = wds[3];
    uint4 o1; o1.x = wds[4]; o1.y = wds[5]; o1.z = wds[6]; o1.w = wds[7];
    *reinterpret_cast<uint4*>(tmpf8 + (size_t)gr * 128 + seg * 32) = o0;
    *reinterpret_cast<uint4*>(tmpf8 + (size_t)gr * 128 + seg * 32 + 16) = o1;
  }
}

// --- gather: 2 rows per VMEM instruction, half-wave per node ----------------
// Wave handles nodes (2i, 2i+1). Lanes 0-31 process node0's csr range, lanes
// 32-63 node1's; each load: half-wave reads its node's edge row as u32
// (32 lanes x 4B = full 128B fp8 row). Scalar csr indices (s_load); one
// cndmask selects the half's scalar row offset. Predicated validity
// multiplier replaces the remainder loop. No cross-lane combine.
__global__ __launch_bounds__(256) void k_gather_f8(const u8* __restrict__ tmpf8,
                                                   const int* __restrict__ csr,
                                                   const int* __restrict__ offs,
                                                   const float* __restrict__ dis,
                                                   const float* __restrict__ bias,
                                                   u16* __restrict__ houtb, int n) {
  int node0 = blockIdx.x * 8 + (threadIdx.x >> 6) * 2;
  if (node0 >= n) return;
  int node1 = (node0 + 1 < n) ? node0 + 1 : node0;  // duplicate benign (same data)
  int lane = threadIdx.x & 63;
  int half = lane >> 5;
  int l32 = lane & 31;
  const u32* tp = reinterpret_cast<const u32*>(tmpf8) + l32;  // per-lane base

  int s0  = __builtin_amdgcn_readfirstlane(offs[node0]);
  int mid = __builtin_amdgcn_readfirstlane(offs[node1]);
  int s1  = __builtin_amdgcn_readfirstlane(offs[node1 + 1]);
  int len0 = mid - s0, len1 = s1 - mid;
  int nbatch = (max(len0, len1) + 7) >> 3;
  int midm1 = max(mid - 1, 0);
  int s1m1  = max(s1 - 1, 0);

  int myNode = half ? node1 : node0;

  f32x4 acc[4];
#pragma unroll
  for (int i = 0; i < 4; ++i) acc[i] = f32x4{0.f, 0.f, 0.f, 0.f};

  // self-loop row (issued first; latency overlaps the loop)
  {
    u32 v = tp[(u32)myNode << 5];
    f32x2 lo = __builtin_amdgcn_cvt_pk_f32_fp8((int)v, false);
    f32x2 hi = __builtin_amdgcn_cvt_pk_f32_fp8((int)v, true);
    acc[0] += f32x4{lo.x, lo.y, hi.x, hi.y};
  }

  for (int b = 0; b < nbatch; ++b) {
    int e0 = s0 + b * 8, e1 = mid + b * 8;
    int ro[8];
    float sel[8];
#pragma unroll
    for (int j = 0; j < 8; ++j) {
      int iA = min(e0 + j, midm1);
      int iB = min(e1 + j, s1m1);
      int roA = __builtin_amdgcn_readfirstlane(csr[iA]) << 5;  // u32-unit row offset
      int roB = __builtin_amdgcn_readfirstlane(csr[iB]) << 5;
      ro[j] = half ? roB : roA;
      float sA = (e0 + j < mid) ? 1.0f : 0.0f;
      float sB = (e1 + j < s1) ? 1.0f : 0.0f;
      sel[j] = half ? sB : sA;
    }
    u32 v[8];
#pragma unroll
    for (int j = 0; j < 8; ++j) v[j] = tp[(u32)ro[j]];
#pragma unroll
    for (int j = 0; j < 8; ++j) {
      f32x2 lo = __builtin_amdgcn_cvt_pk_f32_fp8((int)v[j], false);
      f32x2 hi = __builtin_amdgcn_cvt_pk_f32_fp8((int)v[j], true);
      f32x4 f = {lo.x, lo.y, hi.x, hi.y};
      acc[j & 3] += f * sel[j];
    }
  }

  f32x4 s = (acc[0] + acc[1]) + (acc[2] + acc[3]);
  float dn = (half ? dis[node1] : dis[node0]) * 0.0625f;  // /16 undoes pre-scale
  float4 bb = reinterpret_cast<const float4*>(bias)[l32];
  float r0 = fmaf(dn, s.x, bb.x); r0 = r0 > 0.f ? r0 : 0.f;
  float r1 = fmaf(dn, s.y, bb.y); r1 = r1 > 0.f ? r1 : 0.f;
  float r2 = fmaf(dn, s.z, bb.z); r2 = r2 > 0.f ? r2 : 0.f;
  float r3 = fmaf(dn, s.w, bb.w); r3 = r3 > 0.f ? r3 : 0.f;
  uint2 o;
  o.x = (u32)f2bf(r0) | ((u32)f2bf(r1) << 16);
  o.y = (u32)f2bf(r2) | ((u32)f2bf(r3) << 16);
  // node1==node0 duplicate: both halves write identical data (benign)
  reinterpret_cast<uint2*>(houtb)[(size_t)myNode * 32 + l32] = o;
}

// --- mean-pool column sums (bf16 in, fp32 out); 512 blocks -> 65K atomics ---
__global__ __launch_bounds__(256) void k_pool_bf(const u16* __restrict__ h,
                                                 float* __restrict__ pooled, int n) {
  int lane = threadIdx.x & 63, wv = threadIdx.x >> 6;
  const u32* hp = reinterpret_cast<const u32*>(h);
  float sx = 0.f, sy = 0.f;
  for (int r = blockIdx.x * 4 + wv; r < n; r += gridDim.x * 4) {
    u32 u = hp[(size_t)r * 64 + lane];
    sx += bflo(u); sy += bfhi(u);
  }
  __shared__ float red[2][256];
  red[0][threadIdx.x] = sx;
  red[1][threadIdx.x] = sy;
  __syncthreads();
  if (threadIdx.x < 64) {
    float tx = red[0][threadIdx.x] + red[0][threadIdx.x + 64] +
               red[0][threadIdx.x + 128] + red[0][threadIdx.x + 192];
    float ty = red[1][threadIdx.x] + red[1][threadIdx.x + 64] +
               red[1][threadIdx.x + 128] + red[1][threadIdx.x + 192];
    atomicAdd(&pooled[threadIdx.x * 2], tx);
    atomicAdd(&pooled[threadIdx.x * 2 + 1], ty);
  }
}

__global__ void k_final(const float* __restrict__ pooled, const float* __restrict__ Wfc,
                        const float* __restrict__ bfc, float* __restrict__ out,
                        float invn) {
  int j = threadIdx.x;
  if (j < 32) {
    float acc = 0.f;
    for (int k = 0; k < 128; ++k) acc = fmaf(pooled[k], Wfc[k * 32 + j], acc);
    out[j] = fmaf(acc, invn, bfc[j]);
  }
}

extern "C" void kernel_launch(void* const* d_in, const int* in_sizes, int n_in,
                              void* d_out, int out_size, void* d_ws, size_t ws_size,
                              hipStream_t stream) {
  const float* x   = (const float*)d_in[0];
  const int*   ei  = (const int*)d_in[1];
  const float* W0  = (const float*)d_in[2];
  const float* b0  = (const float*)d_in[3];
  const float* W1  = (const float*)d_in[4];
  const float* b1  = (const float*)d_in[5];
  const float* W2  = (const float*)d_in[6];
  const float* b2  = (const float*)d_in[7];
  const float* Wfc = (const float*)d_in[8];
  const float* bfc = (const float*)d_in[9];

  const int n = in_sizes[0] / 128;
  const int e = in_sizes[1] / 2;
  const int nb = (n + (1 << BKSH) - 1) >> BKSH;

  char* ws = (char*)d_ws;
  size_t off = 0;
  auto alloc = [&](size_t bytes) -> void* {
    void* p = ws + off;
    off = (off + bytes + 255) & ~(size_t)255;
    return p;
  };
  int*   mode      = (int*)alloc(sizeof(int));
  int*   bucketCur = (int*)alloc(NBMAX * 4);
  int*   bucketOff = (int*)alloc((NBMAX + 1) * 4);
  int*   offs      = (int*)alloc((size_t)(n + 1) * 4);
  float* dis       = (float*)alloc((size_t)n * 4);
  int*   csr       = (int*)alloc((size_t)e * 4);
  float* pooled    = (float*)alloc(128 * 4);
  u16*   wp        = (u16*)alloc(3 * 2048 * 8 * 2);
  u8*    tmpf8     = (u8*)alloc((size_t)n * 128);
  u16*   houtb     = (u16*)alloc((size_t)n * 128 * 2);
  int*   pairBuf   = (int*)houtb;  // alias: padded pairs (nb*CAP*8B <= 25.2MB)
                                   // consumed by b_fine before gather0 writes

  k_init<<<2, 256, 0, stream>>>(ei, mode, bucketCur, pooled, e, nb);
  b_scatter<<<(e + SCH - 1) / SCH, 256, 0, stream>>>(ei, mode, bucketCur, pairBuf, e, nb);
  b_bscan2<<<1, 256, 0, stream>>>(bucketCur, bucketOff, nb);
  b_fine<<<nb, 512, 0, stream>>>(pairBuf, bucketCur, bucketOff, offs, dis, csr, n, e);

  k_wpack3<<<24, 256, 0, stream>>>(W0, W1, W2, wp);

  int gg = (n + 63) / 64;
  int gn = (n + 7) / 8;

  // layer 0 (reads fp32 x directly)
  k_gemm_mfma<true><<<gg, 256, 0, stream>>>(x, wp, dis, tmpf8, n);
  k_gather_f8<<<gn, 256, 0, stream>>>(tmpf8, csr, offs, dis, b0, houtb, n);
  // layer 1
  k_gemm_mfma<false><<<gg, 256, 0, stream>>>(houtb, wp + 2048 * 8, dis, tmpf8, n);
  k_gather_f8<<<gn, 256, 0, stream>>>(tmpf8, csr, offs, dis, b1, houtb, n);
  // layer 2
  k_gemm_mfma<false><<<gg, 256, 0, stream>>>(houtb, wp + 2 * 2048 * 8, dis, tmpf8, n);
  k_gather_f8<<<gn, 256, 0, stream>>>(tmpf8, csr, offs, dis, b2, houtb, n);

  k_pool_bf<<<512, 256, 0, stream>>>(houtb, pooled, n);
  k_final<<<1, 32, 0, stream>>>(pooled, Wfc, bfc, (float*)d_out, 1.0f / (float)n);
}